// Round 6
// baseline (168.776 us; speedup 1.0000x reference)
//
#include <hip/hip_runtime.h>
#include <math.h>

#define BB 2
#define NN 1024
#define DD 48
#define DH 12
#define PSTR 52   // 208B row stride: 16B-aligned

// force_mag(dist, mi, mj) lookup table, float2-paired along mj
#define ND 128
#define NM 16
#define D_LO 1.0f
#define D_HI 20.0f
#define DSTEP ((D_HI - D_LO) / (float)(ND - 1))
#define DINV  ((float)(ND - 1) / (D_HI - D_LO))
#define MSTEP (2.0f / (float)(NM - 1))
#define MINV  ((float)(NM - 1) / 2.0f)

__device__ __forceinline__ float gelu_exact(float x) {
    return 0.5f * x * (1.0f + erff(x * 0.70710678118654752f));
}
__device__ __forceinline__ float gelu_fast(float x) {
    float u = x * x;
    float p = __builtin_fmaf(0.044715f * x, u, x);
    float z = 1.5957691216057308f * p;
    float e = __expf(-z);
    return x * __builtin_amdgcn_rcpf(1.0f + e);
}
__device__ __forceinline__ float softplus_f(float x) {
    return (x > 20.0f) ? x : log1pf(expf(x));
}

// ======== prep: blocks [0,256) build table2; blocks [256,272) mass+norm+massT+zero ========
__global__ __launch_bounds__(128) void prep_kernel(
    const float* __restrict__ pos,
    const float* __restrict__ m_w1, const float* __restrict__ m_b1,
    const float* __restrict__ m_w2, const float* __restrict__ m_b2,
    const float* __restrict__ f_w1, const float* __restrict__ f_b1,
    const float* __restrict__ f_w2, const float* __restrict__ f_b2,
    const float* __restrict__ f_w3, const float* __restrict__ f_b3,
    float* __restrict__ mass_out, float* __restrict__ massT,
    float* __restrict__ normn, float* __restrict__ force_acc,
    float2* __restrict__ table2)
{
    int tid = threadIdx.x;
    if (blockIdx.x < 256) {
        __shared__ float sFm[128];
        int e = blockIdx.x * 128 + tid;            // 0..32767
        int mj = e & (NM - 1);
        int mi = (e >> 4) & (NM - 1);
        int di = e >> 8;
        float dist = D_LO + di * DSTEP;
        float vmi = mi * MSTEP, vmj = mj * MSTEP;
        float h1[DD];
        #pragma unroll
        for (int k = 0; k < DD; ++k) {
            float t = f_b1[k] + dist * f_w1[k] + vmi * f_w1[DD + k] + vmj * f_w1[2 * DD + k];
            h1[k] = gelu_fast(t);
        }
        float fm = f_b3[0];
        for (int k = 0; k < DD; ++k) {             // rolled: uniform scalar weight loads
            float t = f_b2[k];
            #pragma unroll
            for (int c = 0; c < DD; ++c) t += h1[c] * f_w2[c * DD + k];
            fm += gelu_fast(t) * f_w3[k];
        }
        sFm[tid] = fm;
        __syncthreads();
        float nbv = ((tid & 15) == 15) ? fm : sFm[tid + 1];  // mj+1 neighbor (mj=15 never deref'd)
        table2[e] = make_float2(fm, nbv);
    } else {
        int p = (blockIdx.x - 256) * 128 + tid;    // 0..2047
        float4* fr = (float4*)(force_acc + (size_t)p * DD);
        float4 z4 = make_float4(0.f, 0.f, 0.f, 0.f);
        #pragma unroll
        for (int k = 0; k < 12; ++k) fr[k] = z4;   // replay-safe zeroing

        const float4* pp = (const float4*)(pos + (size_t)p * DD);
        float x[DD]; float n2 = 0.f;
        #pragma unroll
        for (int k = 0; k < 12; ++k) {
            float4 v = pp[k];
            x[4*k+0] = v.x; x[4*k+1] = v.y; x[4*k+2] = v.z; x[4*k+3] = v.w;
            n2 += v.x*v.x + v.y*v.y + v.z*v.z + v.w*v.w;
        }
        float m2 = m_b2[0];
        #pragma unroll
        for (int k = 0; k < DH; ++k) {
            float h = m_b1[k];
            #pragma unroll
            for (int d = 0; d < DD; ++d) h += x[d] * m_w1[d * DH + k];
            m2 += gelu_exact(h) * m_w2[k];
        }
        float m = softplus_f(m2);
        mass_out[p] = m;
        massT[p] = fminf(fmaxf(m * MINV, 0.f), (float)(NM - 1) - 1e-3f);
        normn[p] = n2;
    }
}

// ======== force: one block = one causal 32x16 tile; 2 pos rows in regs/thread ========
__global__ __launch_bounds__(256) void force_kernel(
    const float* __restrict__ pos, const float* __restrict__ massT,
    const float* __restrict__ normn, const float2* __restrict__ table2,
    float* __restrict__ force_acc)
{
    __shared__ float sPj[16 * PSTR];
    __shared__ float sNj[16];
    __shared__ float sTn[16];
    __shared__ float sRatA[16][17];
    __shared__ float sRatB[16][17];

    // bid -> (b, strip s, j-tile jt): per batch, strip s owns 2s+2 j-tiles,
    // cumulative C(s) = s^2 + s.
    int bid = blockIdx.x;                    // grid = 2*1056
    int b = (bid >= 1056) ? 1 : 0;
    int t = bid - b * 1056;
    int s = (int)((sqrtf(4.0f * (float)t + 1.0f) - 1.0f) * 0.5f);
    while (s * s + s > t) --s;
    while ((s + 1) * (s + 2) <= t) ++s;
    int jt = t - (s * s + s);
    int i0 = s * 32, j0 = jt * 16;

    int tid = threadIdx.x;
    int ti = tid >> 4, tj = tid & 15;
    int u = (tid >> 2) & 3, q = tid & 3;
    int iA = i0 + ti, iB = i0 + 16 + ti;

    // stage j-tile (192 threads x float4) + per-j norm/table-coord
    if (tid < 192) {
        int row = tid / 12, c4 = tid - row * 12;
        const float4* src = (const float4*)(pos + (size_t)(b * NN + j0 + row) * DD);
        *(float4*)&sPj[row * PSTR + 4 * c4] = src[c4];
    }
    if (tid < 16) {
        sNj[tid] = normn[b * NN + j0 + tid];
        sTn[tid] = massT[b * NN + j0 + tid];
    }

    const float* prA = pos + (size_t)(b * NN + iA) * DD;
    const float* prB = pos + (size_t)(b * NN + iB) * DD;
    float piA[DD], piB[DD];
    #pragma unroll
    for (int k = 0; k < 12; ++k) {
        float4 va = ((const float4*)prA)[k];
        float4 vb = ((const float4*)prB)[k];
        piA[4*k+0] = va.x; piA[4*k+1] = va.y; piA[4*k+2] = va.z; piA[4*k+3] = va.w;
        piB[4*k+0] = vb.x; piB[4*k+1] = vb.y; piB[4*k+2] = vb.z; piB[4*k+3] = vb.w;
    }
    float nA = normn[b * NN + iA], nB = normn[b * NN + iB];
    float tmA = massT[b * NN + iA], tmB = massT[b * NN + iB];
    int miA = (int)tmA; float fiA = tmA - miA; int miA16 = miA * NM;
    int miB = (int)tmB; float fiB = tmB - miB; int miB16 = miB * NM;

    __syncthreads();

    // ---- Phase A: dist via norm trick + table lookup, 2 rows/thread ----
    {
        const float4* pj4 = (const float4*)&sPj[tj * PSTR];
        float dA = 0.f, dB = 0.f;
        #pragma unroll
        for (int k = 0; k < 12; ++k) {
            float4 v = pj4[k];
            dA = fmaf(piA[4*k+0], v.x, dA); dA = fmaf(piA[4*k+1], v.y, dA);
            dA = fmaf(piA[4*k+2], v.z, dA); dA = fmaf(piA[4*k+3], v.w, dA);
            dB = fmaf(piB[4*k+0], v.x, dB); dB = fmaf(piB[4*k+1], v.y, dB);
            dB = fmaf(piB[4*k+2], v.z, dB); dB = fmaf(piB[4*k+3], v.w, dB);
        }
        float njv = sNj[tj];
        float tnv = sTn[tj];
        int nj0 = (int)tnv; float fj = tnv - nj0;
        int gj = j0 + tj;

        {   // row A
            float s2 = fmaxf(nA + njv - 2.f * dA, 0.f);
            float dist = fmaxf(sqrtf(s2), 0.01f);
            float td = fminf(fmaxf((dist - D_LO) * DINV, 0.f), (float)(ND - 1) - 1e-3f);
            int di0 = (int)td; float fd = td - di0;
            int idx = di0 * (NM * NM) + miA16 + nj0;
            float2 c00 = table2[idx],            c01 = table2[idx + NM];
            float2 c10 = table2[idx + NM * NM],  c11 = table2[idx + NM * NM + NM];
            float x00 = c00.x + fj * (c00.y - c00.x);
            float x01 = c01.x + fj * (c01.y - c01.x);
            float x10 = c10.x + fj * (c10.y - c10.x);
            float x11 = c11.x + fj * (c11.y - c11.x);
            float y0 = x00 + fiA * (x01 - x00);
            float y1 = x10 + fiA * (x11 - x10);
            float fmv = y0 + fd * (y1 - y0);
            sRatA[ti][tj] = (gj <= iA) ? fmv * __builtin_amdgcn_rcpf(dist) : 0.f;
        }
        {   // row B
            float s2 = fmaxf(nB + njv - 2.f * dB, 0.f);
            float dist = fmaxf(sqrtf(s2), 0.01f);
            float td = fminf(fmaxf((dist - D_LO) * DINV, 0.f), (float)(ND - 1) - 1e-3f);
            int di0 = (int)td; float fd = td - di0;
            int idx = di0 * (NM * NM) + miB16 + nj0;
            float2 c00 = table2[idx],            c01 = table2[idx + NM];
            float2 c10 = table2[idx + NM * NM],  c11 = table2[idx + NM * NM + NM];
            float x00 = c00.x + fj * (c00.y - c00.x);
            float x01 = c01.x + fj * (c01.y - c01.x);
            float x10 = c10.x + fj * (c10.y - c10.x);
            float x11 = c11.x + fj * (c11.y - c11.x);
            float y0 = x00 + fiB * (x01 - x00);
            float y1 = x10 + fiB * (x11 - x10);
            float fmv = y0 + fd * (y1 - y0);
            sRatB[ti][tj] = (gj <= iB) ? fmv * __builtin_amdgcn_rcpf(dist) : 0.f;
        }
    }
    __syncthreads();

    // ---- Phase B: thread=(ti, u over t, q over 12-dim slice): S += r, V += r*pj ----
    float SA = 0.f, SB = 0.f;
    float VA[12], VB[12];
    #pragma unroll
    for (int c = 0; c < 12; ++c) { VA[c] = 0.f; VB[c] = 0.f; }
    #pragma unroll
    for (int k = 0; k < 4; ++k) {
        int t4 = 4 * k + u;
        float rA = sRatA[ti][t4];
        float rB = sRatB[ti][t4];
        SA += rA; SB += rB;
        const float4* pr = (const float4*)&sPj[t4 * PSTR + 12 * q];
        #pragma unroll
        for (int c = 0; c < 3; ++c) {
            float4 v = pr[c];
            VA[4*c+0] = fmaf(rA, v.x, VA[4*c+0]);
            VA[4*c+1] = fmaf(rA, v.y, VA[4*c+1]);
            VA[4*c+2] = fmaf(rA, v.z, VA[4*c+2]);
            VA[4*c+3] = fmaf(rA, v.w, VA[4*c+3]);
            VB[4*c+0] = fmaf(rB, v.x, VB[4*c+0]);
            VB[4*c+1] = fmaf(rB, v.y, VB[4*c+1]);
            VB[4*c+2] = fmaf(rB, v.z, VB[4*c+2]);
            VB[4*c+3] = fmaf(rB, v.w, VB[4*c+3]);
        }
    }

    // reduce over u (lanes differ in tid bits 2-3 -> shuffle offsets 4, 8)
    #pragma unroll
    for (int off = 4; off <= 8; off <<= 1) {
        SA += __shfl_xor(SA, off); SB += __shfl_xor(SB, off);
        #pragma unroll
        for (int c = 0; c < 12; ++c) {
            VA[c] += __shfl_xor(VA[c], off);
            VB[c] += __shfl_xor(VB[c], off);
        }
    }
    if (u == 0) {
        int d0 = 12 * q;
        float* fA = force_acc + (size_t)(b * NN + iA) * DD + d0;
        float* fB = force_acc + (size_t)(b * NN + iB) * DD + d0;
        const float* pA = prA + d0;
        const float* pB = prB + d0;
        #pragma unroll
        for (int c = 0; c < 12; ++c) {
            atomicAdd(&fA[c], pA[c] * SA - VA[c]);
            atomicAdd(&fB[c], pB[c] * SB - VB[c]);
        }
    }
}

// ======== integrate (float4) ========
__global__ void integrate_kernel(const float* __restrict__ pos, const float* __restrict__ vel,
                                 const float* __restrict__ force, const float* __restrict__ mass,
                                 const float* __restrict__ damping_p, const float* __restrict__ dt_p,
                                 float* __restrict__ out) {
    int e4 = blockIdx.x * blockDim.x + threadIdx.x;
    const int N4 = BB * NN * DD / 4;
    if (e4 >= N4) return;
    int p = (e4 * 4) / DD;
    float damping = damping_p[0], dt = dt_p[0];
    float inv = 1.0f / (mass[p] + 0.1f);
    float4 f = ((const float4*)force)[e4];
    float4 v = ((const float4*)vel)[e4];
    float4 x = ((const float4*)pos)[e4];
    float4 nv, np;
    nv.x = damping * v.x + dt * (f.x * inv);
    nv.y = damping * v.y + dt * (f.y * inv);
    nv.z = damping * v.z + dt * (f.z * inv);
    nv.w = damping * v.w + dt * (f.w * inv);
    np.x = x.x + dt * nv.x; np.y = x.y + dt * nv.y;
    np.z = x.z + dt * nv.z; np.w = x.w + dt * nv.w;
    ((float4*)out)[e4] = np;
    ((float4*)out)[N4 + e4] = nv;
}

extern "C" void kernel_launch(void* const* d_in, const int* in_sizes, int n_in,
                              void* d_out, int out_size, void* d_ws, size_t ws_size,
                              hipStream_t stream) {
    const float* pos  = (const float*)d_in[0];
    const float* vel  = (const float*)d_in[1];
    const float* m_w1 = (const float*)d_in[2];
    const float* m_b1 = (const float*)d_in[3];
    const float* m_w2 = (const float*)d_in[4];
    const float* m_b2 = (const float*)d_in[5];
    const float* f_w1 = (const float*)d_in[6];
    const float* f_b1 = (const float*)d_in[7];
    const float* f_w2 = (const float*)d_in[8];
    const float* f_b2 = (const float*)d_in[9];
    const float* f_w3 = (const float*)d_in[10];
    const float* f_b3 = (const float*)d_in[11];
    const float* damping = (const float*)d_in[12];
    const float* dt   = (const float*)d_in[13];

    float* force_ws = (float*)d_ws;                    // 98304 floats
    float* mass_ws  = force_ws + BB * NN * DD;         // 2048
    float* massT_ws = mass_ws + BB * NN;               // 2048
    float* norm_ws  = massT_ws + BB * NN;              // 2048
    float2* table2_ws = (float2*)(norm_ws + BB * NN);  // 32768 float2

    prep_kernel<<<272, 128, 0, stream>>>(pos, m_w1, m_b1, m_w2, m_b2,
                                         f_w1, f_b1, f_w2, f_b2, f_w3, f_b3,
                                         mass_ws, massT_ws, norm_ws, force_ws, table2_ws);

    force_kernel<<<BB * 1056, 256, 0, stream>>>(pos, massT_ws, norm_ws, table2_ws, force_ws);

    integrate_kernel<<<(BB * NN * DD / 4 + 255) / 256, 256, 0, stream>>>(
        pos, vel, force_ws, mass_ws, damping, dt, (float*)d_out);
}

// Round 7
// 49.840 us; speedup vs baseline: 3.3864x; 3.3864x over previous
//
#include <hip/hip_runtime.h>
#include <math.h>

#define BB 2
#define NN 1024
#define DD 48
#define DH 12
#define PSTR 52     // 208B row stride, 16B-aligned
#define NSPLIT 8
#define NSTRIP 64   // 16-row i-strips per batch

// force_mag(dist, mi, mj) lookup table, float2-paired along mj
#define ND 128
#define NM 16
#define D_LO 1.0f
#define D_HI 20.0f
#define DSTEP ((D_HI - D_LO) / (float)(ND - 1))
#define DINV  ((float)(ND - 1) / (D_HI - D_LO))
#define MSTEP (2.0f / (float)(NM - 1))
#define MINV  ((float)(NM - 1) / 2.0f)

__device__ __forceinline__ float gelu_exact(float x) {
    return 0.5f * x * (1.0f + erff(x * 0.70710678118654752f));
}
__device__ __forceinline__ float gelu_fast(float x) {
    float u = x * x;
    float p = __builtin_fmaf(0.044715f * x, u, x);
    float z = 1.5957691216057308f * p;
    float e = __expf(-z);
    return x * __builtin_amdgcn_rcpf(1.0f + e);
}
__device__ __forceinline__ float softplus_f(float x) {
    return (x > 20.0f) ? x : log1pf(expf(x));
}

// ======== prep: blocks [0,256) build table2; blocks [256,272) mass+massT+norm ========
__global__ __launch_bounds__(128) void prep_kernel(
    const float* __restrict__ pos,
    const float* __restrict__ m_w1, const float* __restrict__ m_b1,
    const float* __restrict__ m_w2, const float* __restrict__ m_b2,
    const float* __restrict__ f_w1, const float* __restrict__ f_b1,
    const float* __restrict__ f_w2, const float* __restrict__ f_b2,
    const float* __restrict__ f_w3, const float* __restrict__ f_b3,
    float* __restrict__ mass_out, float* __restrict__ massT,
    float* __restrict__ normn, float2* __restrict__ table2)
{
    int tid = threadIdx.x;
    if (blockIdx.x < 256) {
        __shared__ float sFm[128];
        int e = blockIdx.x * 128 + tid;            // 0..32767
        int mj = e & (NM - 1);
        int mi = (e >> 4) & (NM - 1);
        int di = e >> 8;
        float dist = D_LO + di * DSTEP;
        float vmi = mi * MSTEP, vmj = mj * MSTEP;
        float h1[DD];
        #pragma unroll
        for (int k = 0; k < DD; ++k) {
            float t = f_b1[k] + dist * f_w1[k] + vmi * f_w1[DD + k] + vmj * f_w1[2 * DD + k];
            h1[k] = gelu_fast(t);
        }
        float fm = f_b3[0];
        for (int k = 0; k < DD; ++k) {             // rolled: uniform scalar weight loads
            float t = f_b2[k];
            #pragma unroll
            for (int c = 0; c < DD; ++c) t += h1[c] * f_w2[c * DD + k];
            fm += gelu_fast(t) * f_w3[k];
        }
        sFm[tid] = fm;
        __syncthreads();
        float nbv = ((tid & 15) == 15) ? fm : sFm[tid + 1];  // mj+1 neighbor (mj=15 never deref'd)
        table2[e] = make_float2(fm, nbv);
    } else {
        int p = (blockIdx.x - 256) * 128 + tid;    // 0..2047
        const float4* pp = (const float4*)(pos + (size_t)p * DD);
        float x[DD]; float n2 = 0.f;
        #pragma unroll
        for (int k = 0; k < 12; ++k) {
            float4 v = pp[k];
            x[4*k+0] = v.x; x[4*k+1] = v.y; x[4*k+2] = v.z; x[4*k+3] = v.w;
            n2 += v.x*v.x + v.y*v.y + v.z*v.z + v.w*v.w;
        }
        float m2 = m_b2[0];
        #pragma unroll
        for (int k = 0; k < DH; ++k) {
            float h = m_b1[k];
            #pragma unroll
            for (int d = 0; d < DD; ++d) h += x[d] * m_w1[d * DH + k];
            m2 += gelu_exact(h) * m_w2[k];
        }
        float m = softplus_f(m2);
        mass_out[p] = m;
        massT[p] = fminf(fmaxf(m * MINV, 0.f), (float)(NM - 1) - 1e-3f);
        normn[p] = n2;
    }
}

// ======== force: block = (batch, 16-row strip, j-split); loops its j-tiles ========
// Writes a deterministic 16x48 partial per block -- NO atomics.
__global__ __launch_bounds__(256) void force_kernel(
    const float* __restrict__ pos, const float* __restrict__ massT,
    const float* __restrict__ normn, const float2* __restrict__ table2,
    float* __restrict__ partial)
{
    __shared__ float sPj[2][16 * PSTR];
    __shared__ float sNj[2][16];
    __shared__ float sTn[2][16];
    __shared__ float sRat[16][17];

    int bid = blockIdx.x;                 // 1024 blocks
    int b = bid & 1;
    int r = bid >> 1;                     // 0..511
    int S = (NSTRIP - 1) - (r >> 3);      // heavy strips dispatched first
    int k = r & 7;
    int i0 = S * 16;

    int tid = threadIdx.x;
    int ti = tid >> 4, tj = tid & 15;
    int u = (tid >> 2) & 3, q = tid & 3;
    int gi = i0 + ti;

    int nt = (k <= S) ? ((S - k) >> 3) + 1 : 0;

    // prefetch first j-tile into regs (overlaps i-tile staging)
    float4 stg = make_float4(0.f, 0.f, 0.f, 0.f);
    float stgN = 0.f, stgT = 0.f;
    int srow = (tid < 192) ? tid / 12 : 0;
    int sc4  = (tid < 192) ? tid - srow * 12 : 0;
    int jt = k;
    if (nt > 0) {
        if (tid < 192)
            stg = ((const float4*)(pos + (size_t)(b * NN + jt * 16 + srow) * DD))[sc4];
        if (tid < 16) {
            stgN = normn[b * NN + jt * 16 + tid];
            stgT = massT[b * NN + jt * 16 + tid];
        }
    }

    // stage i-tile through LDS (buf 1) -> per-thread registers
    if (tid < 192)
        *(float4*)&sPj[1][srow * PSTR + 4 * sc4] =
            ((const float4*)(pos + (size_t)(b * NN + i0 + srow) * DD))[sc4];
    __syncthreads();
    float pi[DD];
    {
        const float4* pr = (const float4*)&sPj[1][ti * PSTR];
        #pragma unroll
        for (int kk = 0; kk < 12; ++kk) {
            float4 v = pr[kk];
            pi[4*kk+0] = v.x; pi[4*kk+1] = v.y; pi[4*kk+2] = v.z; pi[4*kk+3] = v.w;
        }
    }
    float nI  = normn[b * NN + gi];
    float tmv = massT[b * NN + gi];
    int mi0 = (int)tmv; float fi = tmv - mi0; int mi16 = mi0 * NM;
    __syncthreads();   // done reading buf 1 as i-tile temp

    float SS = 0.f;
    float V[12];
    #pragma unroll
    for (int c = 0; c < 12; ++c) V[c] = 0.f;

    int cur = 0;
    for (int n = 0; n < nt; ++n) {
        // commit staged j-tile to LDS buf[cur]
        if (tid < 192) *(float4*)&sPj[cur][srow * PSTR + 4 * sc4] = stg;
        if (tid < 16) { sNj[cur][tid] = stgN; sTn[cur][tid] = stgT; }
        __syncthreads();

        int j0 = jt * 16;
        jt += 8;
        if (n + 1 < nt) {   // prefetch next tile (in flight across A+B)
            if (tid < 192)
                stg = ((const float4*)(pos + (size_t)(b * NN + jt * 16 + srow) * DD))[sc4];
            if (tid < 16) {
                stgN = normn[b * NN + jt * 16 + tid];
                stgT = massT[b * NN + jt * 16 + tid];
            }
        }

        // ---- Phase A: thread (ti,tj): dist via norm trick + table lookup ----
        {
            const float4* pj4 = (const float4*)&sPj[cur][tj * PSTR];
            float dP = 0.f;
            #pragma unroll
            for (int kk = 0; kk < 12; ++kk) {
                float4 v = pj4[kk];
                dP = fmaf(pi[4*kk+0], v.x, dP); dP = fmaf(pi[4*kk+1], v.y, dP);
                dP = fmaf(pi[4*kk+2], v.z, dP); dP = fmaf(pi[4*kk+3], v.w, dP);
            }
            float njv = sNj[cur][tj];
            float tnv = sTn[cur][tj];
            int nj0 = (int)tnv; float fj = tnv - nj0;
            float s2 = fmaxf(nI + njv - 2.f * dP, 0.f);
            float dist = fmaxf(sqrtf(s2), 0.01f);
            float td = fminf(fmaxf((dist - D_LO) * DINV, 0.f), (float)(ND - 1) - 1e-3f);
            int di0 = (int)td; float fd = td - di0;
            int idx = di0 * (NM * NM) + mi16 + nj0;
            float2 c00 = table2[idx],            c01 = table2[idx + NM];
            float2 c10 = table2[idx + NM * NM],  c11 = table2[idx + NM * NM + NM];
            float x00 = c00.x + fj * (c00.y - c00.x);
            float x01 = c01.x + fj * (c01.y - c01.x);
            float x10 = c10.x + fj * (c10.y - c10.x);
            float x11 = c11.x + fj * (c11.y - c11.x);
            float y0 = x00 + fi * (x01 - x00);
            float y1 = x10 + fi * (x11 - x10);
            float fmv = y0 + fd * (y1 - y0);
            int gj = j0 + tj;
            sRat[ti][tj] = (gj <= gi) ? fmv * __builtin_amdgcn_rcpf(dist) : 0.f;
        }
        __syncthreads();

        // ---- Phase B: thread (ti,u,q): S += r, V += r*pj over its 4 t's ----
        #pragma unroll
        for (int t4 = 0; t4 < 4; ++t4) {
            int t = 4 * t4 + u;
            float rr = sRat[ti][t];
            SS += rr;
            const float4* pr = (const float4*)&sPj[cur][t * PSTR + 12 * q];
            #pragma unroll
            for (int c = 0; c < 3; ++c) {
                float4 v = pr[c];
                V[4*c+0] = fmaf(rr, v.x, V[4*c+0]);
                V[4*c+1] = fmaf(rr, v.y, V[4*c+1]);
                V[4*c+2] = fmaf(rr, v.z, V[4*c+2]);
                V[4*c+3] = fmaf(rr, v.w, V[4*c+3]);
            }
        }
        cur ^= 1;
        // next iteration's LDS commit targets the other buffer; the sync after
        // that commit also orders Phase B's sRat/sPj reads vs next Phase A.
    }

    // ---- reduce over u (lane bits 2-3) and store partial: f = pi*S - V ----
    #pragma unroll
    for (int off = 4; off <= 8; off <<= 1) {
        SS += __shfl_xor(SS, off);
        #pragma unroll
        for (int c = 0; c < 12; ++c) V[c] += __shfl_xor(V[c], off);
    }
    if (u == 0) {
        size_t base = ((size_t)(k * BB + b) * NN + gi) * DD + 12 * q;
        #pragma unroll
        for (int c = 0; c < 3; ++c) {
            float4 o;
            o.x = pi[12*q + 4*c + 0] * SS - V[4*c+0];
            o.y = pi[12*q + 4*c + 1] * SS - V[4*c+1];
            o.z = pi[12*q + 4*c + 2] * SS - V[4*c+2];
            o.w = pi[12*q + 4*c + 3] * SS - V[4*c+3];
            *(float4*)&partial[base + 4*c] = o;
        }
    }
}

// ======== integrate: sum 8 partial slots + update (float4) ========
__global__ void integrate_kernel(const float* __restrict__ pos, const float* __restrict__ vel,
                                 const float* __restrict__ partial, const float* __restrict__ mass,
                                 const float* __restrict__ damping_p, const float* __restrict__ dt_p,
                                 float* __restrict__ out) {
    int e4 = blockIdx.x * blockDim.x + threadIdx.x;
    const int N4 = BB * NN * DD / 4;
    if (e4 >= N4) return;
    int p = e4 / 12;
    float damping = damping_p[0], dt = dt_p[0];
    float inv = 1.0f / (mass[p] + 0.1f);
    float4 f = make_float4(0.f, 0.f, 0.f, 0.f);
    #pragma unroll
    for (int k = 0; k < NSPLIT; ++k) {
        float4 pv = ((const float4*)partial)[k * N4 + e4];
        f.x += pv.x; f.y += pv.y; f.z += pv.z; f.w += pv.w;
    }
    float4 v = ((const float4*)vel)[e4];
    float4 x = ((const float4*)pos)[e4];
    float4 nv, np;
    nv.x = damping * v.x + dt * (f.x * inv);
    nv.y = damping * v.y + dt * (f.y * inv);
    nv.z = damping * v.z + dt * (f.z * inv);
    nv.w = damping * v.w + dt * (f.w * inv);
    np.x = x.x + dt * nv.x; np.y = x.y + dt * nv.y;
    np.z = x.z + dt * nv.z; np.w = x.w + dt * nv.w;
    ((float4*)out)[e4] = np;
    ((float4*)out)[N4 + e4] = nv;
}

extern "C" void kernel_launch(void* const* d_in, const int* in_sizes, int n_in,
                              void* d_out, int out_size, void* d_ws, size_t ws_size,
                              hipStream_t stream) {
    const float* pos  = (const float*)d_in[0];
    const float* vel  = (const float*)d_in[1];
    const float* m_w1 = (const float*)d_in[2];
    const float* m_b1 = (const float*)d_in[3];
    const float* m_w2 = (const float*)d_in[4];
    const float* m_b2 = (const float*)d_in[5];
    const float* f_w1 = (const float*)d_in[6];
    const float* f_b1 = (const float*)d_in[7];
    const float* f_w2 = (const float*)d_in[8];
    const float* f_b2 = (const float*)d_in[9];
    const float* f_w3 = (const float*)d_in[10];
    const float* f_b3 = (const float*)d_in[11];
    const float* damping = (const float*)d_in[12];
    const float* dt   = (const float*)d_in[13];

    float* partial_ws = (float*)d_ws;                      // 8*98304 floats
    float* mass_ws    = partial_ws + NSPLIT * BB * NN * DD;
    float* massT_ws   = mass_ws + BB * NN;
    float* norm_ws    = massT_ws + BB * NN;
    float2* table2_ws = (float2*)(norm_ws + BB * NN);      // 32768 float2

    prep_kernel<<<272, 128, 0, stream>>>(pos, m_w1, m_b1, m_w2, m_b2,
                                         f_w1, f_b1, f_w2, f_b2, f_w3, f_b3,
                                         mass_ws, massT_ws, norm_ws, table2_ws);

    force_kernel<<<BB * NSTRIP * NSPLIT, 256, 0, stream>>>(pos, massT_ws, norm_ws,
                                                           table2_ws, partial_ws);

    integrate_kernel<<<(BB * NN * DD / 4 + 255) / 256, 256, 0, stream>>>(
        pos, vel, partial_ws, mass_ws, damping, dt, (float*)d_out);
}

// Round 8
// 47.258 us; speedup vs baseline: 3.5713x; 1.0546x over previous
//
#include <hip/hip_runtime.h>
#include <math.h>

#define BB 2
#define NN 1024
#define DD 48
#define DH 12
#define NSLOT 16    // partial slots (splitgroups of 4 waves)

// force_mag(dist, mi, mj) lookup table, float2-paired along mj
#define ND 128
#define NM 16
#define D_LO 1.0f
#define D_HI 20.0f
#define DSTEP ((D_HI - D_LO) / (float)(ND - 1))
#define DINV  ((float)(ND - 1) / (D_HI - D_LO))
#define MSTEP (2.0f / (float)(NM - 1))
#define MINV  ((float)(NM - 1) / 2.0f)

__device__ __forceinline__ float gelu_exact(float x) {
    return 0.5f * x * (1.0f + erff(x * 0.70710678118654752f));
}
__device__ __forceinline__ float gelu_fast(float x) {
    float u = x * x;
    float p = __builtin_fmaf(0.044715f * x, u, x);
    float z = 1.5957691216057308f * p;
    float e = __expf(-z);
    return x * __builtin_amdgcn_rcpf(1.0f + e);
}
__device__ __forceinline__ float softplus_f(float x) {
    return (x > 20.0f) ? x : log1pf(expf(x));
}

// ======== prep: blocks [0,256) build table2; blocks [256,272) mass+nm2 ========
__global__ __launch_bounds__(128) void prep_kernel(
    const float* __restrict__ pos,
    const float* __restrict__ m_w1, const float* __restrict__ m_b1,
    const float* __restrict__ m_w2, const float* __restrict__ m_b2,
    const float* __restrict__ f_w1, const float* __restrict__ f_b1,
    const float* __restrict__ f_w2, const float* __restrict__ f_b2,
    const float* __restrict__ f_w3, const float* __restrict__ f_b3,
    float* __restrict__ mass_out, float2* __restrict__ nm2,
    float2* __restrict__ table2)
{
    int tid = threadIdx.x;
    if (blockIdx.x < 256) {
        __shared__ float sFm[128];
        int e = blockIdx.x * 128 + tid;            // 0..32767
        int mj = e & (NM - 1);
        int mi = (e >> 4) & (NM - 1);
        int di = e >> 8;
        float dist = D_LO + di * DSTEP;
        float vmi = mi * MSTEP, vmj = mj * MSTEP;
        // c-outer / k-inner, fully unrolled: weights -> batched s_loads,
        // t[48] static-indexed -> VGPRs
        float t[DD];
        #pragma unroll
        for (int k = 0; k < DD; ++k) t[k] = f_b2[k];
        #pragma unroll
        for (int c = 0; c < DD; ++c) {
            float h = gelu_fast(f_b1[c] + dist * f_w1[c] + vmi * f_w1[DD + c]
                                + vmj * f_w1[2 * DD + c]);
            #pragma unroll
            for (int k = 0; k < DD; ++k) t[k] = fmaf(h, f_w2[c * DD + k], t[k]);
        }
        float fm = f_b3[0];
        #pragma unroll
        for (int k = 0; k < DD; ++k) fm += gelu_fast(t[k]) * f_w3[k];
        sFm[tid] = fm;
        __syncthreads();
        float nbv = ((tid & 15) == 15) ? fm : sFm[tid + 1];  // mj+1 (mj=15 never deref'd)
        table2[e] = make_float2(fm, nbv);
    } else {
        int p = (blockIdx.x - 256) * 128 + tid;    // 0..2047
        const float4* pp = (const float4*)(pos + (size_t)p * DD);
        float x[DD]; float n2 = 0.f;
        #pragma unroll
        for (int k = 0; k < 12; ++k) {
            float4 v = pp[k];
            x[4*k+0] = v.x; x[4*k+1] = v.y; x[4*k+2] = v.z; x[4*k+3] = v.w;
            n2 += v.x*v.x + v.y*v.y + v.z*v.z + v.w*v.w;
        }
        float m2 = m_b2[0];
        #pragma unroll
        for (int k = 0; k < DH; ++k) {
            float h = m_b1[k];
            #pragma unroll
            for (int d = 0; d < DD; ++d) h += x[d] * m_w1[d * DH + k];
            m2 += gelu_exact(h) * m_w2[k];
        }
        float m = softplus_f(m2);
        mass_out[p] = m;
        float mt = fminf(fmaxf(m * MINV, 0.f), (float)(NM - 1) - 1e-3f);
        nm2[p] = make_float2(n2, mt);
    }
}

// ======== force: 1 wave = (batch, 16-row strip, j-split); no LDS in loop ========
// lane = (li in 16 i-rows, q in 4 12-dim slices). V needs no cross-lane reduce.
__global__ __launch_bounds__(256) void force_kernel(
    const float* __restrict__ pos, const float2* __restrict__ nm2,
    const float2* __restrict__ table2, float* __restrict__ partial)
{
    int bid = blockIdx.x;                 // 2048 blocks
    int b = bid & 1;
    int r = bid >> 1;                     // 0..1023
    int s = 63 - (r >> 4);                // heavy strips dispatched first
    int g = r & 15;                       // splitgroup -> partial slot
    int tid = threadIdx.x;
    int wid = tid >> 6;
    int lane = tid & 63;
    int li = lane >> 2, q = lane & 3;
    int k = g * 4 + wid;                  // j-split 0..63
    int i0 = s * 16;
    int gi = i0 + li;
    int jmax = i0 + 15;

    // pi slice (12 floats) + (norm, massT) for row i
    const float4* prI = (const float4*)(pos + (size_t)(b * NN + gi) * DD) + 3 * q;
    float4 pi0 = prI[0], pi1 = prI[1], pi2 = prI[2];
    float2 nmI = nm2[b * NN + gi];
    int mi0 = (int)nmI.y; float fi = nmI.y - mi0; int mi16 = mi0 * NM;

    float S = 0.f;
    float4 V0 = make_float4(0.f,0.f,0.f,0.f), V1 = V0, V2 = V0;

    // software-pipelined j-loop (stride 64)
    float4 a0, a1, a2; float2 anm;
    if (k <= jmax) {
        const float4* sj = (const float4*)(pos + (size_t)(b * NN + k) * DD) + 3 * q;
        a0 = sj[0]; a1 = sj[1]; a2 = sj[2];
        anm = nm2[b * NN + k];
    }
    for (int j = k; j <= jmax; j += 64) {
        float4 p0 = a0, p1 = a1, p2 = a2; float2 nmJ = anm;
        int jn = j + 64;
        if (jn <= jmax) {      // prefetch next j (stays in flight across compute)
            const float4* sj = (const float4*)(pos + (size_t)(b * NN + jn) * DD) + 3 * q;
            a0 = sj[0]; a1 = sj[1]; a2 = sj[2];
            anm = nm2[b * NN + jn];
        }
        // partial dot (12 dims) + quad reduce
        float dp = pi0.x * p0.x;
        dp = fmaf(pi0.y, p0.y, dp); dp = fmaf(pi0.z, p0.z, dp); dp = fmaf(pi0.w, p0.w, dp);
        dp = fmaf(pi1.x, p1.x, dp); dp = fmaf(pi1.y, p1.y, dp);
        dp = fmaf(pi1.z, p1.z, dp); dp = fmaf(pi1.w, p1.w, dp);
        dp = fmaf(pi2.x, p2.x, dp); dp = fmaf(pi2.y, p2.y, dp);
        dp = fmaf(pi2.z, p2.z, dp); dp = fmaf(pi2.w, p2.w, dp);
        dp += __shfl_xor(dp, 1);
        dp += __shfl_xor(dp, 2);

        float s2 = fmaxf(nmI.x + nmJ.x - 2.f * dp, 0.f);
        float dist = fmaxf(sqrtf(s2), 0.01f);
        float td = fminf(fmaxf((dist - D_LO) * DINV, 0.f), (float)(ND - 1) - 1e-3f);
        int di0 = (int)td; float fd = td - di0;
        int nj0 = (int)nmJ.y; float fj = nmJ.y - nj0;
        int idx = di0 * (NM * NM) + mi16 + nj0;
        float2 c00 = table2[idx],            c01 = table2[idx + NM];
        float2 c10 = table2[idx + NM * NM],  c11 = table2[idx + NM * NM + NM];
        float x00 = c00.x + fj * (c00.y - c00.x);
        float x01 = c01.x + fj * (c01.y - c01.x);
        float x10 = c10.x + fj * (c10.y - c10.x);
        float x11 = c11.x + fj * (c11.y - c11.x);
        float y0 = x00 + fi * (x01 - x00);
        float y1 = x10 + fi * (x11 - x10);
        float fmv = y0 + fd * (y1 - y0);

        float rr = (j <= gi) ? fmv * __builtin_amdgcn_rcpf(dist) : 0.f;
        S += rr;
        V0.x = fmaf(rr, p0.x, V0.x); V0.y = fmaf(rr, p0.y, V0.y);
        V0.z = fmaf(rr, p0.z, V0.z); V0.w = fmaf(rr, p0.w, V0.w);
        V1.x = fmaf(rr, p1.x, V1.x); V1.y = fmaf(rr, p1.y, V1.y);
        V1.z = fmaf(rr, p1.z, V1.z); V1.w = fmaf(rr, p1.w, V1.w);
        V2.x = fmaf(rr, p2.x, V2.x); V2.y = fmaf(rr, p2.y, V2.y);
        V2.z = fmaf(rr, p2.z, V2.z); V2.w = fmaf(rr, p2.w, V2.w);
    }

    // per-wave f-slice = pi*S - V; block-reduce 4 waves -> one partial slot
    __shared__ __align__(16) float red[4][16][48];
    float4 f0, f1, f2;
    f0.x = pi0.x * S - V0.x; f0.y = pi0.y * S - V0.y;
    f0.z = pi0.z * S - V0.z; f0.w = pi0.w * S - V0.w;
    f1.x = pi1.x * S - V1.x; f1.y = pi1.y * S - V1.y;
    f1.z = pi1.z * S - V1.z; f1.w = pi1.w * S - V1.w;
    f2.x = pi2.x * S - V2.x; f2.y = pi2.y * S - V2.y;
    f2.z = pi2.z * S - V2.z; f2.w = pi2.w * S - V2.w;
    float4* rp = (float4*)&red[wid][li][12 * q];
    rp[0] = f0; rp[1] = f1; rp[2] = f2;
    __syncthreads();

    if (tid < 192) {
        int i = tid / 12, c4 = tid - (tid / 12) * 12;
        float4 acc = *(const float4*)&red[0][i][4 * c4];
        #pragma unroll
        for (int w = 1; w < 4; ++w) {
            float4 v = *(const float4*)&red[w][i][4 * c4];
            acc.x += v.x; acc.y += v.y; acc.z += v.z; acc.w += v.w;
        }
        ((float4*)partial)[((size_t)(g * BB + b) * NN + i0 + i) * 12 + c4] = acc;
    }
}

// ======== integrate: sum 16 partial slots + update (float4) ========
__global__ void integrate_kernel(const float* __restrict__ pos, const float* __restrict__ vel,
                                 const float* __restrict__ partial, const float* __restrict__ mass,
                                 const float* __restrict__ damping_p, const float* __restrict__ dt_p,
                                 float* __restrict__ out) {
    int e4 = blockIdx.x * blockDim.x + threadIdx.x;
    const int N4 = BB * NN * DD / 4;
    if (e4 >= N4) return;
    int p = e4 / 12;
    float damping = damping_p[0], dt = dt_p[0];
    float inv = 1.0f / (mass[p] + 0.1f);
    float4 f = make_float4(0.f, 0.f, 0.f, 0.f);
    #pragma unroll
    for (int k = 0; k < NSLOT; ++k) {
        float4 pv = ((const float4*)partial)[(size_t)k * N4 + e4];
        f.x += pv.x; f.y += pv.y; f.z += pv.z; f.w += pv.w;
    }
    float4 v = ((const float4*)vel)[e4];
    float4 x = ((const float4*)pos)[e4];
    float4 nv, np;
    nv.x = damping * v.x + dt * (f.x * inv);
    nv.y = damping * v.y + dt * (f.y * inv);
    nv.z = damping * v.z + dt * (f.z * inv);
    nv.w = damping * v.w + dt * (f.w * inv);
    np.x = x.x + dt * nv.x; np.y = x.y + dt * nv.y;
    np.z = x.z + dt * nv.z; np.w = x.w + dt * nv.w;
    ((float4*)out)[e4] = np;
    ((float4*)out)[N4 + e4] = nv;
}

extern "C" void kernel_launch(void* const* d_in, const int* in_sizes, int n_in,
                              void* d_out, int out_size, void* d_ws, size_t ws_size,
                              hipStream_t stream) {
    const float* pos  = (const float*)d_in[0];
    const float* vel  = (const float*)d_in[1];
    const float* m_w1 = (const float*)d_in[2];
    const float* m_b1 = (const float*)d_in[3];
    const float* m_w2 = (const float*)d_in[4];
    const float* m_b2 = (const float*)d_in[5];
    const float* f_w1 = (const float*)d_in[6];
    const float* f_b1 = (const float*)d_in[7];
    const float* f_w2 = (const float*)d_in[8];
    const float* f_b2 = (const float*)d_in[9];
    const float* f_w3 = (const float*)d_in[10];
    const float* f_b3 = (const float*)d_in[11];
    const float* damping = (const float*)d_in[12];
    const float* dt   = (const float*)d_in[13];

    float* partial_ws = (float*)d_ws;                      // NSLOT*98304 floats
    float* mass_ws    = partial_ws + NSLOT * BB * NN * DD; // 2048
    float2* nm2_ws    = (float2*)(mass_ws + BB * NN);      // 2048 float2
    float2* table2_ws = nm2_ws + BB * NN;                  // 32768 float2

    prep_kernel<<<272, 128, 0, stream>>>(pos, m_w1, m_b1, m_w2, m_b2,
                                         f_w1, f_b1, f_w2, f_b2, f_w3, f_b3,
                                         mass_ws, nm2_ws, table2_ws);

    force_kernel<<<2048, 256, 0, stream>>>(pos, nm2_ws, table2_ws, partial_ws);

    integrate_kernel<<<(BB * NN * DD / 4 + 255) / 256, 256, 0, stream>>>(
        pos, vel, partial_ws, mass_ws, damping, dt, (float*)d_out);
}

// Round 9
// 42.666 us; speedup vs baseline: 3.9558x; 1.1076x over previous
//
#include <hip/hip_runtime.h>
#include <math.h>

#define BB 2
#define NN 1024
#define DD 48
#define DH 12
#define NSLOT 16    // partial slots (splitgroups of 4 waves)

// force_mag(dist, mi, mj) lookup table, float2-paired along mj
#define ND 128
#define NM 16
#define D_LO 1.0f
#define D_HI 20.0f
#define DSTEP ((D_HI - D_LO) / (float)(ND - 1))
#define DINV  ((float)(ND - 1) / (D_HI - D_LO))
#define MSTEP (2.0f / (float)(NM - 1))
#define MINV  ((float)(NM - 1) / 2.0f)

__device__ __forceinline__ float gelu_exact(float x) {
    return 0.5f * x * (1.0f + erff(x * 0.70710678118654752f));
}
__device__ __forceinline__ float gelu_fast(float x) {
    float u = x * x;
    float p = __builtin_fmaf(0.044715f * x, u, x);
    float z = 1.5957691216057308f * p;
    float e = __expf(-z);
    return x * __builtin_amdgcn_rcpf(1.0f + e);
}
__device__ __forceinline__ float softplus_f(float x) {
    return (x > 20.0f) ? x : log1pf(expf(x));
}

// ======== prep: blocks [0,256) build table2 (LDS-staged weights);
//                blocks [256,272) mass+nm2 ========
__global__ __launch_bounds__(128) void prep_kernel(
    const float* __restrict__ pos,
    const float* __restrict__ m_w1, const float* __restrict__ m_b1,
    const float* __restrict__ m_w2, const float* __restrict__ m_b2,
    const float* __restrict__ f_w1, const float* __restrict__ f_b1,
    const float* __restrict__ f_w2, const float* __restrict__ f_b2,
    const float* __restrict__ f_w3, const float* __restrict__ f_b3,
    float* __restrict__ mass_out, float2* __restrict__ nm2,
    float2* __restrict__ table2)
{
    int tid = threadIdx.x;
    if (blockIdx.x < 256) {
        __shared__ float sW2T[DD * DD];     // sW2T[k*48+c] = w2[c][k]
        __shared__ float sW1[3 * DD];
        __shared__ float sB1[DD], sB2[DD], sW3[DD];
        __shared__ float sFm[128];
        for (int e = tid; e < DD * DD; e += 128) {
            int c = e / DD, k = e - c * DD;
            sW2T[k * DD + c] = f_w2[e];
        }
        for (int e = tid; e < 3 * DD; e += 128) sW1[e] = f_w1[e];
        if (tid < DD) { sB1[tid] = f_b1[tid]; sB2[tid] = f_b2[tid]; sW3[tid] = f_w3[tid]; }
        __syncthreads();

        int e = blockIdx.x * 128 + tid;            // 0..32767
        int mj = e & (NM - 1);
        int mi = (e >> 4) & (NM - 1);
        int di = e >> 8;
        float dist = D_LO + di * DSTEP;
        float vmi = mi * MSTEP, vmj = mj * MSTEP;

        float h1[DD];
        #pragma unroll
        for (int k = 0; k < DD; ++k) {
            float t = sB1[k] + dist * sW1[k] + vmi * sW1[DD + k] + vmj * sW1[2 * DD + k];
            h1[k] = gelu_fast(t);
        }
        float fm = f_b3[0];
        #pragma unroll 6
        for (int k = 0; k < DD; ++k) {          // h1 indices compile-time (inner unroll)
            float t = sB2[k];
            const float4* wr = (const float4*)&sW2T[k * DD];
            #pragma unroll
            for (int c4 = 0; c4 < 12; ++c4) {
                float4 w = wr[c4];
                t = fmaf(h1[4*c4+0], w.x, t);
                t = fmaf(h1[4*c4+1], w.y, t);
                t = fmaf(h1[4*c4+2], w.z, t);
                t = fmaf(h1[4*c4+3], w.w, t);
            }
            fm += gelu_fast(t) * sW3[k];
        }
        sFm[tid] = fm;
        __syncthreads();
        float nbv = ((tid & 15) == 15) ? fm : sFm[tid + 1];  // mj+1 (mj=15 never deref'd)
        table2[e] = make_float2(fm, nbv);
    } else {
        int p = (blockIdx.x - 256) * 128 + tid;    // 0..2047
        const float4* pp = (const float4*)(pos + (size_t)p * DD);
        float x[DD]; float n2 = 0.f;
        #pragma unroll
        for (int k = 0; k < 12; ++k) {
            float4 v = pp[k];
            x[4*k+0] = v.x; x[4*k+1] = v.y; x[4*k+2] = v.z; x[4*k+3] = v.w;
            n2 += v.x*v.x + v.y*v.y + v.z*v.z + v.w*v.w;
        }
        float m2 = m_b2[0];
        #pragma unroll
        for (int k = 0; k < DH; ++k) {
            float h = m_b1[k];
            #pragma unroll
            for (int d = 0; d < DD; ++d) h += x[d] * m_w1[d * DH + k];
            m2 += gelu_exact(h) * m_w2[k];
        }
        float m = softplus_f(m2);
        mass_out[p] = m;
        float mt = fminf(fmaxf(m * MINV, 0.f), (float)(NM - 1) - 1e-3f);
        nm2[p] = make_float2(n2, mt);
    }
}

// ======== force: 1 wave = (batch, 16-row strip, j-split); no LDS in loop ========
// lane = (li in 16 i-rows, q in 4 12-dim slices). V needs no cross-lane reduce.
__global__ __launch_bounds__(256) void force_kernel(
    const float* __restrict__ pos, const float2* __restrict__ nm2,
    const float2* __restrict__ table2, float* __restrict__ partial)
{
    int bid = blockIdx.x;                 // 2048 blocks
    int b = bid & 1;
    int r = bid >> 1;                     // 0..1023
    int s = 63 - (r >> 4);                // heavy strips dispatched first
    int g = r & 15;                       // splitgroup -> partial slot
    int tid = threadIdx.x;
    int wid = tid >> 6;
    int lane = tid & 63;
    int li = lane >> 2, q = lane & 3;
    int k = g * 4 + wid;                  // j-split 0..63
    int i0 = s * 16;
    int gi = i0 + li;
    int jmax = i0 + 15;

    // pi slice (12 floats) + (norm, massT) for row i
    const float4* prI = (const float4*)(pos + (size_t)(b * NN + gi) * DD) + 3 * q;
    float4 pi0 = prI[0], pi1 = prI[1], pi2 = prI[2];
    float2 nmI = nm2[b * NN + gi];
    int mi0 = (int)nmI.y; float fi = nmI.y - mi0; int mi16 = mi0 * NM;

    float S = 0.f;
    float4 V0 = make_float4(0.f,0.f,0.f,0.f), V1 = V0, V2 = V0;

    // software-pipelined j-loop (stride 64)
    float4 a0, a1, a2; float2 anm;
    if (k <= jmax) {
        const float4* sj = (const float4*)(pos + (size_t)(b * NN + k) * DD) + 3 * q;
        a0 = sj[0]; a1 = sj[1]; a2 = sj[2];
        anm = nm2[b * NN + k];
    }
    for (int j = k; j <= jmax; j += 64) {
        float4 p0 = a0, p1 = a1, p2 = a2; float2 nmJ = anm;
        int jn = j + 64;
        if (jn <= jmax) {      // prefetch next j (stays in flight across compute)
            const float4* sj = (const float4*)(pos + (size_t)(b * NN + jn) * DD) + 3 * q;
            a0 = sj[0]; a1 = sj[1]; a2 = sj[2];
            anm = nm2[b * NN + jn];
        }
        // partial dot (12 dims) + quad reduce
        float dp = pi0.x * p0.x;
        dp = fmaf(pi0.y, p0.y, dp); dp = fmaf(pi0.z, p0.z, dp); dp = fmaf(pi0.w, p0.w, dp);
        dp = fmaf(pi1.x, p1.x, dp); dp = fmaf(pi1.y, p1.y, dp);
        dp = fmaf(pi1.z, p1.z, dp); dp = fmaf(pi1.w, p1.w, dp);
        dp = fmaf(pi2.x, p2.x, dp); dp = fmaf(pi2.y, p2.y, dp);
        dp = fmaf(pi2.z, p2.z, dp); dp = fmaf(pi2.w, p2.w, dp);
        dp += __shfl_xor(dp, 1);
        dp += __shfl_xor(dp, 2);

        float s2 = fmaxf(nmI.x + nmJ.x - 2.f * dp, 0.f);
        float dist = fmaxf(sqrtf(s2), 0.01f);
        float td = fminf(fmaxf((dist - D_LO) * DINV, 0.f), (float)(ND - 1) - 1e-3f);
        int di0 = (int)td; float fd = td - di0;
        int nj0 = (int)nmJ.y; float fj = nmJ.y - nj0;
        int idx = di0 * (NM * NM) + mi16 + nj0;
        float2 c00 = table2[idx],            c01 = table2[idx + NM];
        float2 c10 = table2[idx + NM * NM],  c11 = table2[idx + NM * NM + NM];
        float x00 = c00.x + fj * (c00.y - c00.x);
        float x01 = c01.x + fj * (c01.y - c01.x);
        float x10 = c10.x + fj * (c10.y - c10.x);
        float x11 = c11.x + fj * (c11.y - c11.x);
        float y0 = x00 + fi * (x01 - x00);
        float y1 = x10 + fi * (x11 - x10);
        float fmv = y0 + fd * (y1 - y0);

        float rr = (j <= gi) ? fmv * __builtin_amdgcn_rcpf(dist) : 0.f;
        S += rr;
        V0.x = fmaf(rr, p0.x, V0.x); V0.y = fmaf(rr, p0.y, V0.y);
        V0.z = fmaf(rr, p0.z, V0.z); V0.w = fmaf(rr, p0.w, V0.w);
        V1.x = fmaf(rr, p1.x, V1.x); V1.y = fmaf(rr, p1.y, V1.y);
        V1.z = fmaf(rr, p1.z, V1.z); V1.w = fmaf(rr, p1.w, V1.w);
        V2.x = fmaf(rr, p2.x, V2.x); V2.y = fmaf(rr, p2.y, V2.y);
        V2.z = fmaf(rr, p2.z, V2.z); V2.w = fmaf(rr, p2.w, V2.w);
    }

    // per-wave f-slice = pi*S - V; block-reduce 4 waves -> one partial slot
    __shared__ __align__(16) float red[4][16][48];
    float4 f0, f1, f2;
    f0.x = pi0.x * S - V0.x; f0.y = pi0.y * S - V0.y;
    f0.z = pi0.z * S - V0.z; f0.w = pi0.w * S - V0.w;
    f1.x = pi1.x * S - V1.x; f1.y = pi1.y * S - V1.y;
    f1.z = pi1.z * S - V1.z; f1.w = pi1.w * S - V1.w;
    f2.x = pi2.x * S - V2.x; f2.y = pi2.y * S - V2.y;
    f2.z = pi2.z * S - V2.z; f2.w = pi2.w * S - V2.w;
    float4* rp = (float4*)&red[wid][li][12 * q];
    rp[0] = f0; rp[1] = f1; rp[2] = f2;
    __syncthreads();

    if (tid < 192) {
        int i = tid / 12, c4 = tid - (tid / 12) * 12;
        float4 acc = *(const float4*)&red[0][i][4 * c4];
        #pragma unroll
        for (int w = 1; w < 4; ++w) {
            float4 v = *(const float4*)&red[w][i][4 * c4];
            acc.x += v.x; acc.y += v.y; acc.z += v.z; acc.w += v.w;
        }
        ((float4*)partial)[((size_t)(g * BB + b) * NN + i0 + i) * 12 + c4] = acc;
    }
}

// ======== integrate: sum 16 partial slots + update (float4) ========
__global__ void integrate_kernel(const float* __restrict__ pos, const float* __restrict__ vel,
                                 const float* __restrict__ partial, const float* __restrict__ mass,
                                 const float* __restrict__ damping_p, const float* __restrict__ dt_p,
                                 float* __restrict__ out) {
    int e4 = blockIdx.x * blockDim.x + threadIdx.x;
    const int N4 = BB * NN * DD / 4;
    if (e4 >= N4) return;
    int p = e4 / 12;
    float damping = damping_p[0], dt = dt_p[0];
    float inv = 1.0f / (mass[p] + 0.1f);
    float4 f = make_float4(0.f, 0.f, 0.f, 0.f);
    #pragma unroll
    for (int k = 0; k < NSLOT; ++k) {
        float4 pv = ((const float4*)partial)[(size_t)k * N4 + e4];
        f.x += pv.x; f.y += pv.y; f.z += pv.z; f.w += pv.w;
    }
    float4 v = ((const float4*)vel)[e4];
    float4 x = ((const float4*)pos)[e4];
    float4 nv, np;
    nv.x = damping * v.x + dt * (f.x * inv);
    nv.y = damping * v.y + dt * (f.y * inv);
    nv.z = damping * v.z + dt * (f.z * inv);
    nv.w = damping * v.w + dt * (f.w * inv);
    np.x = x.x + dt * nv.x; np.y = x.y + dt * nv.y;
    np.z = x.z + dt * nv.z; np.w = x.w + dt * nv.w;
    ((float4*)out)[e4] = np;
    ((float4*)out)[N4 + e4] = nv;
}

extern "C" void kernel_launch(void* const* d_in, const int* in_sizes, int n_in,
                              void* d_out, int out_size, void* d_ws, size_t ws_size,
                              hipStream_t stream) {
    const float* pos  = (const float*)d_in[0];
    const float* vel  = (const float*)d_in[1];
    const float* m_w1 = (const float*)d_in[2];
    const float* m_b1 = (const float*)d_in[3];
    const float* m_w2 = (const float*)d_in[4];
    const float* m_b2 = (const float*)d_in[5];
    const float* f_w1 = (const float*)d_in[6];
    const float* f_b1 = (const float*)d_in[7];
    const float* f_w2 = (const float*)d_in[8];
    const float* f_b2 = (const float*)d_in[9];
    const float* f_w3 = (const float*)d_in[10];
    const float* f_b3 = (const float*)d_in[11];
    const float* damping = (const float*)d_in[12];
    const float* dt   = (const float*)d_in[13];

    float* partial_ws = (float*)d_ws;                      // NSLOT*98304 floats
    float* mass_ws    = partial_ws + NSLOT * BB * NN * DD; // 2048
    float2* nm2_ws    = (float2*)(mass_ws + BB * NN);      // 2048 float2
    float2* table2_ws = nm2_ws + BB * NN;                  // 32768 float2

    prep_kernel<<<272, 128, 0, stream>>>(pos, m_w1, m_b1, m_w2, m_b2,
                                         f_w1, f_b1, f_w2, f_b2, f_w3, f_b3,
                                         mass_ws, nm2_ws, table2_ws);

    force_kernel<<<2048, 256, 0, stream>>>(pos, nm2_ws, table2_ws, partial_ws);

    integrate_kernel<<<(BB * NN * DD / 4 + 255) / 256, 256, 0, stream>>>(
        pos, vel, partial_ws, mass_ws, damping, dt, (float*)d_out);
}

// Round 10
// 41.326 us; speedup vs baseline: 4.0840x; 1.0324x over previous
//
#include <hip/hip_runtime.h>
#include <math.h>

#define BB 2
#define NN 1024
#define DD 48
#define DH 12
#define NSLOT 16    // partial slots (splitgroups of 4 waves)

// force_mag(dist, mi, mj) lookup table, float2-paired along mj
#define ND 128
#define NM 16
#define D_LO 1.0f
#define D_HI 20.0f
#define DSTEP ((D_HI - D_LO) / (float)(ND - 1))
#define DINV  ((float)(ND - 1) / (D_HI - D_LO))
#define MSTEP (2.0f / (float)(NM - 1))
#define MINV  ((float)(NM - 1) / 2.0f)

__device__ __forceinline__ float gelu_exact(float x) {
    return 0.5f * x * (1.0f + erff(x * 0.70710678118654752f));
}
__device__ __forceinline__ float gelu_fast(float x) {
    float u = x * x;
    float p = __builtin_fmaf(0.044715f * x, u, x);
    float z = 1.5957691216057308f * p;
    float e = __expf(-z);
    return x * __builtin_amdgcn_rcpf(1.0f + e);
}
__device__ __forceinline__ float softplus_f(float x) {
    return (x > 20.0f) ? x : log1pf(expf(x));
}

// ======== prep: quad-of-lanes per table entry / per particle ========
// blocks [0,512): table2 (64 entries/block); blocks [512,544): mass+nm2 (64/block)
__global__ __launch_bounds__(256) void prep_kernel(
    const float* __restrict__ pos,
    const float* __restrict__ m_w1, const float* __restrict__ m_b1,
    const float* __restrict__ m_w2, const float* __restrict__ m_b2,
    const float* __restrict__ f_w1, const float* __restrict__ f_b1,
    const float* __restrict__ f_w2, const float* __restrict__ f_b2,
    const float* __restrict__ f_w3, const float* __restrict__ f_b3,
    float* __restrict__ mass_out, float2* __restrict__ nm2,
    float2* __restrict__ table2)
{
    int tid = threadIdx.x;
    int el = tid >> 2, r = tid & 3;        // quad-local: entry-in-block, k/d-slice
    if (blockIdx.x < 512) {
        __shared__ float sFm[64];
        int e = blockIdx.x * 64 + el;      // 0..32767
        int mj = e & (NM - 1);
        int mi = (e >> 4) & (NM - 1);
        int di = e >> 8;
        float dist = D_LO + di * DSTEP;
        float vmi = mi * MSTEP, vmj = mj * MSTEP;

        // t[12]: this lane's 12 k-accumulators (k = 12r + m), init with b2 slice
        float t[12];
        {
            const float4* b2 = (const float4*)(f_b2 + 12 * r);
            float4 a = b2[0], b = b2[1], c = b2[2];
            t[0]=a.x; t[1]=a.y; t[2]=a.z; t[3]=a.w;
            t[4]=b.x; t[5]=b.y; t[6]=b.z; t[7]=b.w;
            t[8]=c.x; t[9]=c.y; t[10]=c.z; t[11]=c.w;
        }
        // c-outer: compute h1c per-lane (cheap), FMA into 12 independent accs.
        // w2 row slices from global (L1-resident, 4 distinct addrs per wave).
        #pragma unroll 4
        for (int c = 0; c < DD; ++c) {
            float h = gelu_fast(f_b1[c] + dist * f_w1[c] + vmi * f_w1[DD + c]
                                + vmj * f_w1[2 * DD + c]);
            const float4* wr = (const float4*)(f_w2 + c * DD + 12 * r);
            float4 w0 = wr[0], w1 = wr[1], w2v = wr[2];
            t[0] = fmaf(h, w0.x, t[0]);  t[1] = fmaf(h, w0.y, t[1]);
            t[2] = fmaf(h, w0.z, t[2]);  t[3] = fmaf(h, w0.w, t[3]);
            t[4] = fmaf(h, w1.x, t[4]);  t[5] = fmaf(h, w1.y, t[5]);
            t[6] = fmaf(h, w1.z, t[6]);  t[7] = fmaf(h, w1.w, t[7]);
            t[8] = fmaf(h, w2v.x, t[8]); t[9] = fmaf(h, w2v.y, t[9]);
            t[10] = fmaf(h, w2v.z, t[10]); t[11] = fmaf(h, w2v.w, t[11]);
        }
        float fm;
        {
            const float4* w3p = (const float4*)(f_w3 + 12 * r);
            float4 a = w3p[0], b = w3p[1], c = w3p[2];
            fm  = gelu_fast(t[0]) * a.x + gelu_fast(t[1]) * a.y
                + gelu_fast(t[2]) * a.z + gelu_fast(t[3]) * a.w
                + gelu_fast(t[4]) * b.x + gelu_fast(t[5]) * b.y
                + gelu_fast(t[6]) * b.z + gelu_fast(t[7]) * b.w
                + gelu_fast(t[8]) * c.x + gelu_fast(t[9]) * c.y
                + gelu_fast(t[10]) * c.z + gelu_fast(t[11]) * c.w;
        }
        fm += __shfl_xor(fm, 1);
        fm += __shfl_xor(fm, 2);
        fm += f_b3[0];
        if (r == 0) sFm[el] = fm;
        __syncthreads();
        if (tid < 64) {
            float v = sFm[tid];
            float nbv = ((tid & 15) == 15) ? v : sFm[tid + 1];  // mj+1 (mj=15 never deref'd)
            table2[blockIdx.x * 64 + tid] = make_float2(v, nbv);
        }
    } else {
        int p = (blockIdx.x - 512) * 64 + el;   // 0..2047
        // lane r owns dims [12r, 12r+12) of particle p's row (quad covers 48)
        const float4* xp = (const float4*)(pos + (size_t)p * DD + 12 * r);
        float4 x0 = xp[0], x1 = xp[1], x2 = xp[2];
        float xs[12];
        xs[0]=x0.x; xs[1]=x0.y; xs[2]=x0.z; xs[3]=x0.w;
        xs[4]=x1.x; xs[5]=x1.y; xs[6]=x1.z; xs[7]=x1.w;
        xs[8]=x2.x; xs[9]=x2.y; xs[10]=x2.z; xs[11]=x2.w;
        float n2 = 0.f;
        #pragma unroll
        for (int j = 0; j < 12; ++j) n2 = fmaf(xs[j], xs[j], n2);
        n2 += __shfl_xor(n2, 1);
        n2 += __shfl_xor(n2, 2);

        // distributed h: t[k] = sum over this lane's 12 d's of x_d * w1[d][k]
        float t[12];
        #pragma unroll
        for (int k = 0; k < 12; ++k) t[k] = 0.f;
        #pragma unroll
        for (int j = 0; j < 12; ++j) {
            const float4* wr = (const float4*)(m_w1 + (size_t)(12 * r + j) * DH);
            float4 a = wr[0], b = wr[1], c = wr[2];
            float xj = xs[j];
            t[0] = fmaf(xj, a.x, t[0]);  t[1] = fmaf(xj, a.y, t[1]);
            t[2] = fmaf(xj, a.z, t[2]);  t[3] = fmaf(xj, a.w, t[3]);
            t[4] = fmaf(xj, b.x, t[4]);  t[5] = fmaf(xj, b.y, t[5]);
            t[6] = fmaf(xj, b.z, t[6]);  t[7] = fmaf(xj, b.w, t[7]);
            t[8] = fmaf(xj, c.x, t[8]);  t[9] = fmaf(xj, c.y, t[9]);
            t[10] = fmaf(xj, c.z, t[10]); t[11] = fmaf(xj, c.w, t[11]);
        }
        #pragma unroll
        for (int k = 0; k < 12; ++k) {
            t[k] += __shfl_xor(t[k], 1);
            t[k] += __shfl_xor(t[k], 2);
        }
        float m2 = m_b2[0];
        #pragma unroll
        for (int k = 0; k < 12; ++k)
            m2 += gelu_exact(t[k] + m_b1[k]) * m_w2[k];
        if (r == 0) {
            float m = softplus_f(m2);
            mass_out[p] = m;
            float mt = fminf(fmaxf(m * MINV, 0.f), (float)(NM - 1) - 1e-3f);
            nm2[p] = make_float2(n2, mt);
        }
    }
}

// ======== force: 1 wave = (batch, 16-row strip, j-split); no LDS in loop ========
// lane = (li in 16 i-rows, q in 4 12-dim slices). V needs no cross-lane reduce.
__global__ __launch_bounds__(256) void force_kernel(
    const float* __restrict__ pos, const float2* __restrict__ nm2,
    const float2* __restrict__ table2, float* __restrict__ partial)
{
    int bid = blockIdx.x;                 // 2048 blocks
    int b = bid & 1;
    int r = bid >> 1;                     // 0..1023
    int s = 63 - (r >> 4);                // heavy strips dispatched first
    int g = r & 15;                       // splitgroup -> partial slot
    int tid = threadIdx.x;
    int wid = tid >> 6;
    int lane = tid & 63;
    int li = lane >> 2, q = lane & 3;
    int k = g * 4 + wid;                  // j-split 0..63
    int i0 = s * 16;
    int gi = i0 + li;
    int jmax = i0 + 15;

    // pi slice (12 floats) + (norm, massT) for row i
    const float4* prI = (const float4*)(pos + (size_t)(b * NN + gi) * DD) + 3 * q;
    float4 pi0 = prI[0], pi1 = prI[1], pi2 = prI[2];
    float2 nmI = nm2[b * NN + gi];
    int mi0 = (int)nmI.y; float fi = nmI.y - mi0; int mi16 = mi0 * NM;

    float S = 0.f;
    float4 V0 = make_float4(0.f,0.f,0.f,0.f), V1 = V0, V2 = V0;

    // software-pipelined j-loop (stride 64)
    float4 a0, a1, a2; float2 anm;
    if (k <= jmax) {
        const float4* sj = (const float4*)(pos + (size_t)(b * NN + k) * DD) + 3 * q;
        a0 = sj[0]; a1 = sj[1]; a2 = sj[2];
        anm = nm2[b * NN + k];
    }
    for (int j = k; j <= jmax; j += 64) {
        float4 p0 = a0, p1 = a1, p2 = a2; float2 nmJ = anm;
        int jn = j + 64;
        if (jn <= jmax) {      // prefetch next j (stays in flight across compute)
            const float4* sj = (const float4*)(pos + (size_t)(b * NN + jn) * DD) + 3 * q;
            a0 = sj[0]; a1 = sj[1]; a2 = sj[2];
            anm = nm2[b * NN + jn];
        }
        // partial dot (12 dims) + quad reduce
        float dp = pi0.x * p0.x;
        dp = fmaf(pi0.y, p0.y, dp); dp = fmaf(pi0.z, p0.z, dp); dp = fmaf(pi0.w, p0.w, dp);
        dp = fmaf(pi1.x, p1.x, dp); dp = fmaf(pi1.y, p1.y, dp);
        dp = fmaf(pi1.z, p1.z, dp); dp = fmaf(pi1.w, p1.w, dp);
        dp = fmaf(pi2.x, p2.x, dp); dp = fmaf(pi2.y, p2.y, dp);
        dp = fmaf(pi2.z, p2.z, dp); dp = fmaf(pi2.w, p2.w, dp);
        dp += __shfl_xor(dp, 1);
        dp += __shfl_xor(dp, 2);

        float s2 = fmaxf(nmI.x + nmJ.x - 2.f * dp, 0.f);
        float dist = fmaxf(sqrtf(s2), 0.01f);
        float td = fminf(fmaxf((dist - D_LO) * DINV, 0.f), (float)(ND - 1) - 1e-3f);
        int di0 = (int)td; float fd = td - di0;
        int nj0 = (int)nmJ.y; float fj = nmJ.y - nj0;
        int idx = di0 * (NM * NM) + mi16 + nj0;
        float2 c00 = table2[idx],            c01 = table2[idx + NM];
        float2 c10 = table2[idx + NM * NM],  c11 = table2[idx + NM * NM + NM];
        float x00 = c00.x + fj * (c00.y - c00.x);
        float x01 = c01.x + fj * (c01.y - c01.x);
        float x10 = c10.x + fj * (c10.y - c10.x);
        float x11 = c11.x + fj * (c11.y - c11.x);
        float y0 = x00 + fi * (x01 - x00);
        float y1 = x10 + fi * (x11 - x10);
        float fmv = y0 + fd * (y1 - y0);

        float rr = (j <= gi) ? fmv * __builtin_amdgcn_rcpf(dist) : 0.f;
        S += rr;
        V0.x = fmaf(rr, p0.x, V0.x); V0.y = fmaf(rr, p0.y, V0.y);
        V0.z = fmaf(rr, p0.z, V0.z); V0.w = fmaf(rr, p0.w, V0.w);
        V1.x = fmaf(rr, p1.x, V1.x); V1.y = fmaf(rr, p1.y, V1.y);
        V1.z = fmaf(rr, p1.z, V1.z); V1.w = fmaf(rr, p1.w, V1.w);
        V2.x = fmaf(rr, p2.x, V2.x); V2.y = fmaf(rr, p2.y, V2.y);
        V2.z = fmaf(rr, p2.z, V2.z); V2.w = fmaf(rr, p2.w, V2.w);
    }

    // per-wave f-slice = pi*S - V; block-reduce 4 waves -> one partial slot
    __shared__ __align__(16) float red[4][16][48];
    float4 f0, f1, f2;
    f0.x = pi0.x * S - V0.x; f0.y = pi0.y * S - V0.y;
    f0.z = pi0.z * S - V0.z; f0.w = pi0.w * S - V0.w;
    f1.x = pi1.x * S - V1.x; f1.y = pi1.y * S - V1.y;
    f1.z = pi1.z * S - V1.z; f1.w = pi1.w * S - V1.w;
    f2.x = pi2.x * S - V2.x; f2.y = pi2.y * S - V2.y;
    f2.z = pi2.z * S - V2.z; f2.w = pi2.w * S - V2.w;
    float4* rp = (float4*)&red[wid][li][12 * q];
    rp[0] = f0; rp[1] = f1; rp[2] = f2;
    __syncthreads();

    if (tid < 192) {
        int i = tid / 12, c4 = tid - (tid / 12) * 12;
        float4 acc = *(const float4*)&red[0][i][4 * c4];
        #pragma unroll
        for (int w = 1; w < 4; ++w) {
            float4 v = *(const float4*)&red[w][i][4 * c4];
            acc.x += v.x; acc.y += v.y; acc.z += v.z; acc.w += v.w;
        }
        ((float4*)partial)[((size_t)(g * BB + b) * NN + i0 + i) * 12 + c4] = acc;
    }
}

// ======== integrate: sum 16 partial slots + update (float4) ========
__global__ void integrate_kernel(const float* __restrict__ pos, const float* __restrict__ vel,
                                 const float* __restrict__ partial, const float* __restrict__ mass,
                                 const float* __restrict__ damping_p, const float* __restrict__ dt_p,
                                 float* __restrict__ out) {
    int e4 = blockIdx.x * blockDim.x + threadIdx.x;
    const int N4 = BB * NN * DD / 4;
    if (e4 >= N4) return;
    int p = e4 / 12;
    float damping = damping_p[0], dt = dt_p[0];
    float inv = 1.0f / (mass[p] + 0.1f);
    float4 f = make_float4(0.f, 0.f, 0.f, 0.f);
    #pragma unroll
    for (int k = 0; k < NSLOT; ++k) {
        float4 pv = ((const float4*)partial)[(size_t)k * N4 + e4];
        f.x += pv.x; f.y += pv.y; f.z += pv.z; f.w += pv.w;
    }
    float4 v = ((const float4*)vel)[e4];
    float4 x = ((const float4*)pos)[e4];
    float4 nv, np;
    nv.x = damping * v.x + dt * (f.x * inv);
    nv.y = damping * v.y + dt * (f.y * inv);
    nv.z = damping * v.z + dt * (f.z * inv);
    nv.w = damping * v.w + dt * (f.w * inv);
    np.x = x.x + dt * nv.x; np.y = x.y + dt * nv.y;
    np.z = x.z + dt * nv.z; np.w = x.w + dt * nv.w;
    ((float4*)out)[e4] = np;
    ((float4*)out)[N4 + e4] = nv;
}

extern "C" void kernel_launch(void* const* d_in, const int* in_sizes, int n_in,
                              void* d_out, int out_size, void* d_ws, size_t ws_size,
                              hipStream_t stream) {
    const float* pos  = (const float*)d_in[0];
    const float* vel  = (const float*)d_in[1];
    const float* m_w1 = (const float*)d_in[2];
    const float* m_b1 = (const float*)d_in[3];
    const float* m_w2 = (const float*)d_in[4];
    const float* m_b2 = (const float*)d_in[5];
    const float* f_w1 = (const float*)d_in[6];
    const float* f_b1 = (const float*)d_in[7];
    const float* f_w2 = (const float*)d_in[8];
    const float* f_b2 = (const float*)d_in[9];
    const float* f_w3 = (const float*)d_in[10];
    const float* f_b3 = (const float*)d_in[11];
    const float* damping = (const float*)d_in[12];
    const float* dt   = (const float*)d_in[13];

    float* partial_ws = (float*)d_ws;                      // NSLOT*98304 floats
    float* mass_ws    = partial_ws + NSLOT * BB * NN * DD; // 2048
    float2* nm2_ws    = (float2*)(mass_ws + BB * NN);      // 2048 float2
    float2* table2_ws = nm2_ws + BB * NN;                  // 32768 float2

    prep_kernel<<<544, 256, 0, stream>>>(pos, m_w1, m_b1, m_w2, m_b2,
                                         f_w1, f_b1, f_w2, f_b2, f_w3, f_b3,
                                         mass_ws, nm2_ws, table2_ws);

    force_kernel<<<2048, 256, 0, stream>>>(pos, nm2_ws, table2_ws, partial_ws);

    integrate_kernel<<<(BB * NN * DD / 4 + 255) / 256, 256, 0, stream>>>(
        pos, vel, partial_ws, mass_ws, damping, dt, (float*)d_out);
}